// Round 1
// 1067.971 us; speedup vs baseline: 1.1312x; 1.1312x over previous
//
#include <hip/hip_runtime.h>
#include <math.h>

// Problem constants (Encoder_4776003633446)
#define S_  1024
#define D_  1024
#define Hh  16
#define DKk 64
#define Bb  2
#define Ff  4096
#define Ll  4

typedef __bf16 bf16_t;
using bf16x4 = __attribute__((ext_vector_type(4))) __bf16;
using bf16x8 = __attribute__((ext_vector_type(8))) __bf16;
using f32x4  = __attribute__((ext_vector_type(4))) float;

#define AS1 __attribute__((address_space(1)))
#define AS3 __attribute__((address_space(3)))

#define MD_ ((size_t)2048 * 1024)

// async global->LDS, 16B per lane (dest = wave-uniform base + lane*16)
__device__ __forceinline__ void gld_lds16(const bf16_t* g, bf16_t* l)
{
    __builtin_amdgcn_global_load_lds((AS1 void*)g, (AS3 void*)l, 16, 0, 0);
}

// ---------------------------------------------------------------------------
// Embedding + sinusoidal positional encoding; dual write fp32 + bf16
// ---------------------------------------------------------------------------
__global__ __launch_bounds__(256) void embed_kernel(const int* __restrict__ tokens,
                                                    const float* __restrict__ emb,
                                                    float* __restrict__ X,
                                                    bf16_t* __restrict__ Xh)
{
    const int row = blockIdx.x;            // b*S + s
    const int s   = row & (S_ - 1);
    const int tok = tokens[row];
    const float* e = emb + (size_t)tok * D_;
    const float LN10000 = 9.210340371976184f;
    #pragma unroll
    for (int i = 0; i < 4; ++i) {
        int d = threadIdx.x + 256 * i;
        int half = d >> 1;
        float div = expf(-((float)(2 * half) / (float)D_) * LN10000);
        float ang = (float)s * div;
        float pe = (d & 1) ? cosf(ang) : sinf(ang);
        float v = e[d] + pe;
        X [(size_t)row * D_ + d] = v;
        Xh[(size_t)row * D_ + d] = (bf16_t)v;
    }
}

// ---------------------------------------------------------------------------
// Transpose + cast, batched over z (layers): in fp32 [K][N] -> out bf16 [N][K]
// 32x32 tile per block, 256 threads.
// ---------------------------------------------------------------------------
__device__ __forceinline__ void transpose_tile(const float* __restrict__ in,
                                               bf16_t* __restrict__ out,
                                               int K, int N, int n0, int k0)
{
    __shared__ float T[32][33];
    const int t = threadIdx.x;
    const int r = t >> 3;
    const int c = (t & 7) * 4;

    float4 v = *(const float4*)(in + (size_t)(k0 + r) * N + n0 + c);
    T[r][c + 0] = v.x; T[r][c + 1] = v.y; T[r][c + 2] = v.z; T[r][c + 3] = v.w;
    __syncthreads();

    bf16x4 o = { (bf16_t)T[c + 0][r], (bf16_t)T[c + 1][r],
                 (bf16_t)T[c + 2][r], (bf16_t)T[c + 3][r] };
    *(bf16x4*)(out + (size_t)(n0 + r) * K + k0 + c) = o;
}

// z in [0,16): l = z>>2, which = z&3 (q,k,v,o). All 1024x1024.
__global__ __launch_bounds__(256) void transpose_qkvo_kernel(const float* __restrict__ Wq,
                                                             const float* __restrict__ Wk,
                                                             const float* __restrict__ Wv,
                                                             const float* __restrict__ Wo,
                                                             bf16_t* __restrict__ WQKVt,
                                                             bf16_t* __restrict__ Wot)
{
    const int z = blockIdx.z;
    const int l = z >> 2;
    const int which = z & 3;
    const float* src = (which == 0 ? Wq : which == 1 ? Wk : which == 2 ? Wv : Wo)
                       + (size_t)l * D_ * D_;
    bf16_t* dst = (which < 3) ? WQKVt + (size_t)l * 3072 * D_ + (size_t)which * D_ * D_
                              : Wot + (size_t)l * D_ * D_;
    transpose_tile(src, dst, D_, D_, blockIdx.x * 32, blockIdx.y * 32);
}

// z = layer; in [K][N] at z*K*N, out [N][K] at z*K*N
__global__ __launch_bounds__(256) void transpose_batch_kernel(const float* __restrict__ in,
                                                              bf16_t* __restrict__ out,
                                                              int K, int N)
{
    const size_t off = (size_t)blockIdx.z * K * N;
    transpose_tile(in + off, out + off, K, N, blockIdx.x * 32, blockIdx.y * 32);
}

// ---------------------------------------------------------------------------
// Concat QKV biases: out[l][0:1024]=bq[l], [1024:2048]=bk[l], [2048:3072]=bv[l]
// ---------------------------------------------------------------------------
__global__ __launch_bounds__(256) void concat_bias_kernel(const float* __restrict__ bq,
                                                          const float* __restrict__ bk,
                                                          const float* __restrict__ bv,
                                                          float* __restrict__ out)
{
    const int id = blockIdx.x * 256 + threadIdx.x;   // < L*3072
    const int l  = id / 3072;
    const int j  = id % 3072;
    float v;
    if (j < 1024)      v = bq[l * 1024 + j];
    else if (j < 2048) v = bk[l * 1024 + j - 1024];
    else               v = bv[l * 1024 + j - 2048];
    out[id] = v;
}

// ---------------------------------------------------------------------------
// bf16 MFMA GEMM (m97 "gemm_bt" structure), tiled BM x BN, split-K capable:
//   C[2048,N] = A[2048,Kfull] @ Bt[N,Kfull]^T
// blockIdx.z = K-chunk; each chunk covers Kc columns, fp32 partial output at
// Cv + z*2048*N (split path requires fp32 out, no GELU).
// 256 threads = 4 waves (2x2), wave tile (BM/2)x(BN/2), 16x16x32 bf16 MFMA,
// BK=32, global_load_lds width-16 staging, 2-barrier K-loop.
// flags: 1=bias (applied by chunk 0), 2=exact GELU, 4=bf16 output
// ---------------------------------------------------------------------------
template<int BM, int BN>
__global__ __launch_bounds__(256) void gemm_bf16_kernel(const bf16_t* __restrict__ A,
                                                        const bf16_t* __restrict__ Bt,
                                                        const float* __restrict__ bias,
                                                        void* __restrict__ Cv,
                                                        int N, int Kfull, int Kc, int flags)
{
    constexpr int MI = BM / 32;              // per-wave 16-row subtiles
    constexpr int NI = BN / 32;              // per-wave 16-col subtiles
    __shared__ bf16_t As[BM * 32];
    __shared__ bf16_t Bs[BN * 32];

    const int t    = threadIdx.x;
    const int w    = t >> 6;
    const int lane = t & 63;
    const int l15  = lane & 15;
    const int q8   = lane >> 4;
    const int wm   = w >> 1;                 // 0..1
    const int wn   = w & 1;                  // 0..1

    const int bm = blockIdx.y * BM;
    const int bn = blockIdx.x * BN;
    const int kz = blockIdx.z;

    const int lr4 = lane >> 2;               // 0..15 (row within 16-row issue)
    const int lc8 = (lane & 3) * 8;          // 0,8,16,24

    f32x4 acc[MI][NI] = {};

    const int kbeg = kz * Kc;
    const int kend = kbeg + Kc;
    for (int k0 = kbeg; k0 < kend; k0 += 32) {
        // stage A tile BMx32: each wave BM/4 rows in BM/64 issues of 16 rows
        #pragma unroll
        for (int u = 0; u < BM / 64; ++u) {
            const int row0 = w * (BM / 4) + u * 16;
            gld_lds16(A + (size_t)(bm + row0 + lr4) * Kfull + k0 + lc8,
                      As + row0 * 32);
        }
        // stage B tile BNx32
        #pragma unroll
        for (int u = 0; u < BN / 64; ++u) {
            const int row0 = w * (BN / 4) + u * 16;
            gld_lds16(Bt + (size_t)(bn + row0 + lr4) * Kfull + k0 + lc8,
                      Bs + row0 * 32);
        }
        __syncthreads();   // drains vmcnt(0): DMA'd LDS visible

        bf16x8 af[MI], bf[NI];
        #pragma unroll
        for (int mi = 0; mi < MI; ++mi)
            af[mi] = *(const bf16x8*)(As + (wm * (BM / 2) + mi * 16 + l15) * 32 + q8 * 8);
        #pragma unroll
        for (int ni = 0; ni < NI; ++ni)
            bf[ni] = *(const bf16x8*)(Bs + (wn * (BN / 2) + ni * 16 + l15) * 32 + q8 * 8);

        #pragma unroll
        for (int mi = 0; mi < MI; ++mi)
            #pragma unroll
            for (int ni = 0; ni < NI; ++ni)
                acc[mi][ni] = __builtin_amdgcn_mfma_f32_16x16x32_bf16(
                                  af[mi], bf[ni], acc[mi][ni], 0, 0, 0);
        __syncthreads();   // all reads done before next stage overwrites
    }

    // epilogue: C/D layout row=q8*4+r, col=l15
    float* Cf = (float*)Cv + (size_t)kz * 2048 * N;
    #pragma unroll
    for (int mi = 0; mi < MI; ++mi) {
        #pragma unroll
        for (int ni = 0; ni < NI; ++ni) {
            const int n = bn + wn * (BN / 2) + ni * 16 + l15;
            const float bv_ = ((flags & 1) && kz == 0) ? bias[n] : 0.f;
            #pragma unroll
            for (int r = 0; r < 4; ++r) {
                const int m = bm + wm * (BM / 2) + mi * 16 + q8 * 4 + r;
                float v = acc[mi][ni][r] + bv_;
                if (flags & 2) v = 0.5f * v * (1.0f + erff(v * 0.70710678118654752f));
                if (flags & 4) ((bf16_t*)Cv)[(size_t)m * N + n] = (bf16_t)v;
                else           Cf[(size_t)m * N + n] = v;
            }
        }
    }
}

// ---------------------------------------------------------------------------
// Flash attention, bf16 MFMA 16x16x32. QKV fused input [B*S][3072]
// (Q at +0, K at +1024, V at +2048). Output CTX bf16 [B*S][1024].
// ---------------------------------------------------------------------------
#define AST 72
#define LDQ 3072

__global__ __launch_bounds__(256) void attn_mfma_kernel(const bf16_t* __restrict__ QKV,
                                                        const int* __restrict__ tokens,
                                                        bf16_t* __restrict__ Octx)
{
    const int qt = blockIdx.x;
    const int h  = blockIdx.y;
    const int b  = blockIdx.z;
    const int t    = threadIdx.x;
    const int wave = t >> 6;
    const int lane = t & 63;
    const int l15  = lane & 15;
    const int q8   = lane >> 4;

    __shared__ bf16_t Ks[64][AST];
    __shared__ bf16_t VsT[64][AST];
    __shared__ bf16_t Ps[4][16][AST];

    const bf16_t* Qp = QKV + 0;
    const bf16_t* Kp = QKV + 1024;
    const bf16_t* Vp = QKV + 2048;

    const int q0 = qt * 64 + wave * 16;
    bf16x8 qf0, qf1;
    {
        const bf16_t* qp = Qp + ((size_t)(b * S_ + q0 + l15)) * LDQ + h * 64 + q8 * 8;
        qf0 = *(const bf16x8*)(qp);
        qf1 = *(const bf16x8*)(qp + 32);
    }

    f32x4 Oacc[4] = {};
    float m_run[4], l_run[4];
    #pragma unroll
    for (int r = 0; r < 4; ++r) { m_run[r] = -INFINITY; l_run[r] = 0.f; }

    for (int jt = 0; jt < S_ / 64; ++jt) {
        __syncthreads();
        {
            const bf16_t* kb = Kp + ((size_t)(b * S_ + jt * 64)) * LDQ + h * 64;
            #pragma unroll
            for (int u = 0; u < 2; ++u) {
                int id = t + 256 * u;
                int r  = id >> 3;
                int c  = (id & 7) * 8;
                *(uint4*)&Ks[r][c] = *(const uint4*)(kb + (size_t)r * LDQ + c);
            }
        }
        {
            const bf16_t* vb = Vp + ((size_t)(b * S_ + jt * 64)) * LDQ + h * 64;
            const int j  = lane;
            const int d0 = wave * 16;
            #pragma unroll
            for (int u = 0; u < 2; ++u) {
                bf16x8 vv = *(const bf16x8*)(vb + (size_t)j * LDQ + d0 + u * 8);
                #pragma unroll
                for (int e = 0; e < 8; ++e)
                    VsT[d0 + u * 8 + e][j] = vv[e];
            }
        }
        __syncthreads();

        float sc[4][4];
        #pragma unroll
        for (int nt = 0; nt < 4; ++nt) {
            const bf16_t* kp = &Ks[nt * 16 + l15][q8 * 8];
            bf16x8 b0 = *(const bf16x8*)(kp);
            bf16x8 b1 = *(const bf16x8*)(kp + 32);
            f32x4 a = {};
            a = __builtin_amdgcn_mfma_f32_16x16x32_bf16(qf0, b0, a, 0, 0, 0);
            a = __builtin_amdgcn_mfma_f32_16x16x32_bf16(qf1, b1, a, 0, 0, 0);
            const int jg = jt * 64 + nt * 16 + l15;
            const float msk = (tokens[b * S_ + jg] == 0) ? -1e9f : 0.f;
            #pragma unroll
            for (int r = 0; r < 4; ++r) sc[nt][r] = a[r] * 0.125f + msk;
        }

        float alpha[4];
        #pragma unroll
        for (int r = 0; r < 4; ++r) {
            float mx = fmaxf(fmaxf(sc[0][r], sc[1][r]), fmaxf(sc[2][r], sc[3][r]));
            #pragma unroll
            for (int o = 1; o < 16; o <<= 1) mx = fmaxf(mx, __shfl_xor(mx, o));
            const float mn = fmaxf(m_run[r], mx);
            alpha[r] = __expf(m_run[r] - mn);
            m_run[r] = mn;
            float s = 0.f;
            #pragma unroll
            for (int nt = 0; nt < 4; ++nt) {
                float p = __expf(sc[nt][r] - mn);
                sc[nt][r] = p;
                s += p;
            }
            #pragma unroll
            for (int o = 1; o < 16; o <<= 1) s += __shfl_xor(s, o);
            l_run[r] = l_run[r] * alpha[r] + s;
        }

        #pragma unroll
        for (int nt = 0; nt < 4; ++nt)
            #pragma unroll
            for (int r = 0; r < 4; ++r)
                Ps[wave][q8 * 4 + r][nt * 16 + l15] = (bf16_t)sc[nt][r];

        bf16x8 pf0 = *(const bf16x8*)&Ps[wave][l15][q8 * 8];
        bf16x8 pf1 = *(const bf16x8*)&Ps[wave][l15][32 + q8 * 8];

        #pragma unroll
        for (int dt = 0; dt < 4; ++dt) {
            #pragma unroll
            for (int r = 0; r < 4; ++r) Oacc[dt][r] *= alpha[r];
            const bf16_t* vp = &VsT[dt * 16 + l15][q8 * 8];
            bf16x8 v0 = *(const bf16x8*)(vp);
            bf16x8 v1 = *(const bf16x8*)(vp + 32);
            Oacc[dt] = __builtin_amdgcn_mfma_f32_16x16x32_bf16(pf0, v0, Oacc[dt], 0, 0, 0);
            Oacc[dt] = __builtin_amdgcn_mfma_f32_16x16x32_bf16(pf1, v1, Oacc[dt], 0, 0, 0);
        }
    }

    #pragma unroll
    for (int dt = 0; dt < 4; ++dt) {
        #pragma unroll
        for (int r = 0; r < 4; ++r) {
            const int qg = q0 + q8 * 4 + r;
            Octx[((size_t)(b * S_ + qg)) * D_ + h * 64 + dt * 16 + l15] =
                (bf16_t)(Oacc[dt][r] / l_run[r]);
        }
    }
}

// ---------------------------------------------------------------------------
// Residual add + (sum of NP split-K partials) + LayerNorm; dual write fp32+bf16
// ---------------------------------------------------------------------------
template<int NP>
__global__ __launch_bounds__(256) void add_ln_kernel(const float* __restrict__ R,
                                                     const float* __restrict__ T,
                                                     const float* __restrict__ g,
                                                     const float* __restrict__ bta,
                                                     float* __restrict__ out,
                                                     bf16_t* __restrict__ outh)
{
    const int row = blockIdx.x;
    const int t = threadIdx.x;
    const float* r  = R + (size_t)row * D_;
    const float* tp = T + (size_t)row * D_;

    float v[4];
    float s = 0.f;
    #pragma unroll
    for (int i = 0; i < 4; ++i) {
        int d = t + 256 * i;
        float acc = r[d];
        #pragma unroll
        for (int p = 0; p < NP; ++p) acc += tp[p * MD_ + d];
        v[i] = acc;
        s += acc;
    }

    __shared__ float red[8];
    #pragma unroll
    for (int o = 32; o > 0; o >>= 1) s += __shfl_xor(s, o);
    if ((t & 63) == 0) red[t >> 6] = s;
    __syncthreads();
    const float mean = (red[0] + red[1] + red[2] + red[3]) * (1.0f / D_);

    float vs = 0.f;
    #pragma unroll
    for (int i = 0; i < 4; ++i) { float d = v[i] - mean; vs += d * d; }
    #pragma unroll
    for (int o = 32; o > 0; o >>= 1) vs += __shfl_xor(vs, o);
    if ((t & 63) == 0) red[4 + (t >> 6)] = vs;
    __syncthreads();
    const float var = (red[4] + red[5] + red[6] + red[7]) * (1.0f / D_);
    const float inv = rsqrtf(var + 1e-5f);

    #pragma unroll
    for (int i = 0; i < 4; ++i) {
        int d = t + 256 * i;
        float o = (v[i] - mean) * inv * g[d] + bta[d];
        out [(size_t)row * D_ + d] = o;
        outh[(size_t)row * D_ + d] = (bf16_t)o;
    }
}

// ---------------------------------------------------------------------------
extern "C" void kernel_launch(void* const* d_in, const int* in_sizes, int n_in,
                              void* d_out, int out_size, void* d_ws, size_t ws_size,
                              hipStream_t stream)
{
    const int*   tokens = (const int*)  d_in[0];
    const float* emb    = (const float*)d_in[1];
    const float* Wq     = (const float*)d_in[2];
    const float* bq     = (const float*)d_in[3];
    const float* Wk     = (const float*)d_in[4];
    const float* bk     = (const float*)d_in[5];
    const float* Wv     = (const float*)d_in[6];
    const float* bv     = (const float*)d_in[7];
    const float* Wo     = (const float*)d_in[8];
    const float* bo     = (const float*)d_in[9];
    const float* ln1g   = (const float*)d_in[10];
    const float* ln1b   = (const float*)d_in[11];
    const float* W1     = (const float*)d_in[12];
    const float* W2     = (const float*)d_in[13];
    const float* ln2g   = (const float*)d_in[14];
    const float* ln2b   = (const float*)d_in[15];

    const int M = Bb * S_;                       // 2048
    const size_t MD = (size_t)M * D_;

    // ---- workspace layout (~172 MB) ----
    uint8_t* p = (uint8_t*)d_ws;
    float*  X     = (float*)p;           p += MD * 4;                       // 8 MB
    float*  T1    = (float*)p;           p += MD * 4 * 4;                   // 32 MB (4 split-K slots)
    bf16_t* Xh    = (bf16_t*)p;          p += MD * 2;                       // 4 MB
    bf16_t* QKVh  = (bf16_t*)p;          p += (size_t)M * 3072 * 2;         // 12 MB
    bf16_t* CTXh  = (bf16_t*)p;          p += MD * 2;                       // 4 MB
    bf16_t* HBh   = (bf16_t*)p;          p += (size_t)M * Ff * 2;           // 16 MB
    bf16_t* WQKVt = (bf16_t*)p;          p += (size_t)Ll * 3072 * D_ * 2;   // 24 MB
    bf16_t* Wot   = (bf16_t*)p;          p += (size_t)Ll * D_ * D_ * 2;     // 8 MB
    bf16_t* W1t   = (bf16_t*)p;          p += (size_t)Ll * Ff * D_ * 2;     // 32 MB
    bf16_t* W2t   = (bf16_t*)p;          p += (size_t)Ll * D_ * Ff * 2;     // 32 MB
    float*  bqkv  = (float*)p;           p += (size_t)Ll * 3072 * 4;        // 48 KB

    // prologue: embedding, biases, ALL weight transposes (no loop dependency)
    embed_kernel<<<M, 256, 0, stream>>>(tokens, emb, X, Xh);
    concat_bias_kernel<<<Ll * 3072 / 256, 256, 0, stream>>>(bq, bk, bv, bqkv);
    transpose_qkvo_kernel<<<dim3(32, 32, 16), 256, 0, stream>>>(Wq, Wk, Wv, Wo, WQKVt, Wot);
    transpose_batch_kernel<<<dim3(Ff / 32, D_ / 32, Ll), 256, 0, stream>>>(W1, W1t, D_, Ff);
    transpose_batch_kernel<<<dim3(D_ / 32, Ff / 32, Ll), 256, 0, stream>>>(W2, W2t, Ff, D_);

    for (int l = 0; l < Ll; ++l) {
        const bf16_t* WQKVt_l = WQKVt + (size_t)l * 3072 * D_;
        const bf16_t* Wot_l   = Wot   + (size_t)l * D_ * D_;
        const bf16_t* W1t_l   = W1t   + (size_t)l * Ff * D_;
        const bf16_t* W2t_l   = W2t   + (size_t)l * D_ * Ff;

        // QKV fused: [2048,1024] @ [1024,3072] -> bf16 [2048,3072]
        // 64x128 tiles: 24x32 = 768 blocks = 3/CU
        gemm_bf16_kernel<64, 128><<<dim3(3072 / 128, M / 64), 256, 0, stream>>>(
            Xh, WQKVt_l, bqkv + l * 3072, QKVh, 3072, D_, D_, 1 | 4);

        attn_mfma_kernel<<<dim3(S_ / 64, Hh, Bb), 256, 0, stream>>>(QKVh, tokens, CTXh);

        // Wo: split-K x2 -> fp32 partials T1[0..1] (+bias on chunk 0)
        gemm_bf16_kernel<128, 64><<<dim3(D_ / 64, M / 128, 2), 256, 0, stream>>>(
            CTXh, Wot_l, bo + (size_t)l * D_, T1, D_, D_, D_ / 2, 1);

        add_ln_kernel<2><<<M, 256, 0, stream>>>(X, T1, ln1g + (size_t)l * D_,
                                                ln1b + (size_t)l * D_, X, Xh);

        // W1 + GELU: -> bf16 HBh (128x128 tiles, 512 blocks)
        gemm_bf16_kernel<128, 128><<<dim3(Ff / 128, M / 128), 256, 0, stream>>>(
            Xh, W1t_l, nullptr, HBh, Ff, D_, D_, 2 | 4);

        // W2: split-K x4 -> fp32 partials T1[0..3] (1024 blocks = 4/CU)
        gemm_bf16_kernel<128, 64><<<dim3(D_ / 64, M / 128, 4), 256, 0, stream>>>(
            HBh, W2t_l, nullptr, T1, D_, Ff, Ff / 4, 0);

        float* dst = (l == Ll - 1) ? (float*)d_out : X;
        add_ln_kernel<4><<<M, 256, 0, stream>>>(X, T1, ln2g + (size_t)l * D_,
                                                ln2b + (size_t)l * D_, dst, Xh);
    }
}